// Round 15
// baseline (390.851 us; speedup 1.0000x reference)
//
#include <hip/hip_runtime.h>
#include <hip/hip_bf16.h>

typedef __attribute__((ext_vector_type(8))) short bf16x8;
typedef __attribute__((ext_vector_type(4))) float f32x4;
typedef unsigned short u16;

constexpr int NSEQ = 16384;
constexpr int KD   = 4096;
constexpr int NQ   = 512;     // q cols
constexpr int NCOL = 640;     // q (512) + k (128)
constexpr int BM   = 128;
constexpr int BN   = 160;
constexpr int BK   = 64;
constexpr int KHALF = 2048;
constexpr int NKS  = KHALF / BK;              // 32 K-steps per block
constexpr int TILE_CHUNKS = BN * BK * 2 / 16; // 1280 16B chunks per W tile
constexpr int WCONV_THREADS = 2 * 4 * NKS * TILE_CHUNKS;   // 327,680

// ---- f32 -> bf16 (RTNE) pack helpers -------------------------------------
__device__ __forceinline__ unsigned bf_round(float x) {
    unsigned u = __builtin_bit_cast(unsigned, x);
    unsigned r = u + 0x7FFFu + ((u >> 16) & 1u);
    return r >> 16;
}
__device__ __forceinline__ unsigned pk2(float lo, float hi) {
    return bf_round(lo) | (bf_round(hi) << 16);
}
__device__ __forceinline__ float bfu(unsigned u) {
    return __builtin_bit_cast(float, u << 16);
}

// ---- Kernel 1: W -> bf16, pre-swizzled per-(kh,nb,tt) glds tiles ---------
// Tile = 160 rows x 64 k bf16 = 1280 chunks. Chunk c: n = c>>3 (row),
// sp = c&7 (PHYSICAL k-slot). Content = logical slot sp ^ (n&7)  =>  after
// linear glds, LDS[n*128 + phys*16] holds logical slot (phys ^ (n&7)).
__global__ __launch_bounds__(256) void wconv_kernel(
    const float* __restrict__ qw, const float* __restrict__ kw,
    u16* __restrict__ Wst)
{
    int g = blockIdx.x * 256 + threadIdx.x;
    int tile = g / TILE_CHUNKS;          // 0..255
    int c    = g - tile * TILE_CHUNKS;
    int n  = c >> 3;
    int sp = c & 7;
    int tt = tile & 31;
    int nb = (tile >> 5) & 3;
    int kh = tile >> 7;
    int ng = nb * BN + n;
    int k0 = kh * KHALF + tt * BK + ((sp ^ (n & 7)) << 3);
    const float* src = (ng < NQ) ? (qw + (size_t)ng * KD + k0)
                                 : (kw + (size_t)(ng - NQ) * KD + k0);
    float4 v0 = *(const float4*)(src);
    float4 v1 = *(const float4*)(src + 4);
    int4 o;
    o.x = (int)pk2(v0.x, v0.y);
    o.y = (int)pk2(v0.z, v0.w);
    o.z = (int)pk2(v1.x, v1.y);
    o.w = (int)pk2(v1.z, v1.w);
    *(int4*)(Wst + (size_t)g * 8) = o;
}

// ---- Kernel 2: m97-structure GEMM: glds + 3 blocks/CU ---------------------
// grid 1024 = 128 mblk x 4 nb x 2 kh. xcd=b&7: kh=xcd&1, mblk-group=xcd>>1;
// nb-siblings (same mblk) adjacent in dispatch -> share A-tile via L2.
// 256 thr / 4 waves; wave tile 64x80; acc[4][5]. Per K-step (BK=64):
// lgkm-drain + sync; glds B (5/thr) + A f32->bf16 ds_write; EXPLICIT
// vmcnt(0)+lgkm(0) drain + sync (R14's race: implicit drain was the only
// unverified ordering — now forced); 18 ds_read_b128 + 40 MFMA per wave.
__global__ __launch_bounds__(256, 3) void gemm_kernel(
    const float* __restrict__ hid, const u16* __restrict__ Wst,
    u16* __restrict__ P0, u16* __restrict__ P1)
{
    __shared__ __align__(16) char smem[16384 + 20480];   // A | B = 36 KB
    char* sA = smem;
    char* sB = smem + 16384;

    const int t    = threadIdx.x;
    const int lane = t & 63;
    const int wid  = t >> 6;        // 0..3
    const int wm   = wid >> 1;      // M half (64 rows)
    const int wn   = wid & 1;       // N half (80 cols)

    const int b    = blockIdx.x;
    const int xcd  = b & 7;
    const int kh   = xcd & 1;
    const int idx  = b >> 3;        // 0..127
    const int nb   = idx & 3;
    const int mblk = (xcd >> 1) * 32 + (idx >> 2);   // 0..127
    const int row0 = mblk * BM;
    const int col0 = nb * BN;

    const float* hk = hid + (size_t)row0 * KD + kh * KHALF;
    const u16* wt0  = Wst + (size_t)(kh * 128 + nb * 32) * TILE_CHUNKS * 8;
    u16* P = kh ? P1 : P0;

    f32x4 acc[4][5] = {};

    // A staging: thread t -> row ar (0..127), half hf (32 k-elems)
    const int ar = t >> 1;
    const int hf = t & 1;
    const float* gA = hk + (size_t)ar * KD + hf * 32;
    const int swzA_w = (ar ^ (ar >> 3)) & 7;
    char* aw = sA + ar * 128;

    // fragment read params
    const int bn = lane & 15;
    const int sl = lane >> 4;       // 0..3

#pragma unroll 1
    for (int tt = 0; tt < NKS; ++tt) {
        // B1: all reads of previous tile done (explicit own-lgkm drain first)
        asm volatile("s_waitcnt lgkmcnt(0)" ::: "memory");
        __syncthreads();

        // ---- stage B: 5 glds chunks per thread (linear dest) ----
        const u16* tp = wt0 + (size_t)tt * (TILE_CHUNKS * 8);
        #pragma unroll
        for (int it = 0; it < 5; ++it)
            __builtin_amdgcn_global_load_lds(
                (const __attribute__((address_space(1))) void*)(tp + (size_t)(it * 256 + t) * 8),
                (__attribute__((address_space(3))) void*)(sB + it * 4096 + wid * 1024),
                16, 0, 0);

        // ---- stage A: 8 float4 f32, cvt, 4 swizzled ds_write_b128 ----
        {
            const float* ga = gA + tt * BK;
            float4 v0 = *(const float4*)(ga);
            float4 v1 = *(const float4*)(ga + 4);
            float4 v2 = *(const float4*)(ga + 8);
            float4 v3 = *(const float4*)(ga + 12);
            float4 v4 = *(const float4*)(ga + 16);
            float4 v5 = *(const float4*)(ga + 20);
            float4 v6 = *(const float4*)(ga + 24);
            float4 v7 = *(const float4*)(ga + 28);
            int4 c0, c1, c2, c3;
            c0.x = (int)pk2(v0.x, v0.y);  c0.y = (int)pk2(v0.z, v0.w);
            c0.z = (int)pk2(v1.x, v1.y);  c0.w = (int)pk2(v1.z, v1.w);
            c1.x = (int)pk2(v2.x, v2.y);  c1.y = (int)pk2(v2.z, v2.w);
            c1.z = (int)pk2(v3.x, v3.y);  c1.w = (int)pk2(v3.z, v3.w);
            c2.x = (int)pk2(v4.x, v4.y);  c2.y = (int)pk2(v4.z, v4.w);
            c2.z = (int)pk2(v5.x, v5.y);  c2.w = (int)pk2(v5.z, v5.w);
            c3.x = (int)pk2(v6.x, v6.y);  c3.y = (int)pk2(v6.z, v6.w);
            c3.z = (int)pk2(v7.x, v7.y);  c3.w = (int)pk2(v7.z, v7.w);
            *(int4*)(aw + (((hf * 4 + 0) ^ swzA_w) << 4)) = c0;
            *(int4*)(aw + (((hf * 4 + 1) ^ swzA_w) << 4)) = c1;
            *(int4*)(aw + (((hf * 4 + 2) ^ swzA_w) << 4)) = c2;
            *(int4*)(aw + (((hf * 4 + 3) ^ swzA_w) << 4)) = c3;
        }

        // B2: FORCE drain of glds (vmcnt) and ds_write (lgkm) before reads
        asm volatile("s_waitcnt vmcnt(0) lgkmcnt(0)" ::: "memory");
        __syncthreads();

        // ---- compute: 2 k-halves x (4 A-frags, 5 B-frags, 20 MFMA) ----
        #pragma unroll
        for (int kk = 0; kk < 2; ++kk) {
            bf16x8 af[4];
            #pragma unroll
            for (int m = 0; m < 4; ++m) {
                const int row = wm * 64 + m * 16 + bn;
                const int ph  = (kk * 4 + sl) ^ ((row ^ (row >> 3)) & 7);
                af[m] = *(const bf16x8*)(sA + row * 128 + ph * 16);
            }
            #pragma unroll
            for (int f = 0; f < 5; ++f) {
                const int n  = wn * 80 + f * 16 + bn;
                const int ph = (kk * 4 + sl) ^ (n & 7);
                bf16x8 bf = *(const bf16x8*)(sB + n * 128 + ph * 16);
                acc[0][f] = __builtin_amdgcn_mfma_f32_16x16x32_bf16(af[0], bf, acc[0][f], 0, 0, 0);
                acc[1][f] = __builtin_amdgcn_mfma_f32_16x16x32_bf16(af[1], bf, acc[1][f], 0, 0, 0);
                acc[2][f] = __builtin_amdgcn_mfma_f32_16x16x32_bf16(af[2], bf, acc[2][f], 0, 0, 0);
                acc[3][f] = __builtin_amdgcn_mfma_f32_16x16x32_bf16(af[3], bf, acc[3][f], 0, 0, 0);
            }
        }
    }

    // epilogue: bf16 partial-P write. C/D: col=lane&15, row=(lane>>4)*4+j
    const int crow = (lane >> 4) << 2;
    const int ccol = lane & 15;
    #pragma unroll
    for (int m = 0; m < 4; ++m)
        #pragma unroll
        for (int f = 0; f < 5; ++f)
            #pragma unroll
            for (int j = 0; j < 4; ++j)
                P[(size_t)(row0 + wm * 64 + m * 16 + crow + j) * NCOL
                  + col0 + wn * 80 + f * 16 + ccol] = (u16)bf_round(acc[m][f][j]);
}

// ---- Kernel 3: gating epilogue (reads two bf16 partial-P halves) ----------
__global__ __launch_bounds__(256) void gate_kernel(
    const u16* __restrict__ P0, const u16* __restrict__ P1,
    const float* __restrict__ qb,
    const float* __restrict__ qnw, const float* __restrict__ knw,
    const float* __restrict__ kbase, const float* __restrict__ bb,
    float* __restrict__ out)
{
    __shared__ float skb[8 * 16 * 16];
    __shared__ float sqb[512];
    __shared__ float sb[32];
    __shared__ float snw[32];

    int tid = threadIdx.x;
    for (int i = tid; i < 2048; i += 256) skb[i] = kbase[i];
    for (int i = tid; i < 512;  i += 256) sqb[i] = qb[i];
    if (tid < 32) sb[tid] = bb[tid];
    if (tid < 16) snw[tid] = qnw[tid];
    else if (tid < 32) snw[tid] = knw[tid - 16];
    __syncthreads();

    int gid = blockIdx.x * 256 + tid;
    int tok = gid >> 5;
    int hh  = (gid >> 2) & 7;
    int g   = gid & 3;

    const u16* r0 = P0 + (size_t)tok * NCOL;
    const u16* r1 = P1 + (size_t)tok * NCOL;
    const int qoff = (hh * 4 + g) * 16;

    // q row = P0 + P1 + bias, then RMSNorm
    float q[16];
    float ss = 0.f;
    {
        int4 a0 = *(const int4*)(r0 + qoff);
        int4 a1 = *(const int4*)(r0 + qoff + 8);
        int4 b0 = *(const int4*)(r1 + qoff);
        int4 b1 = *(const int4*)(r1 + qoff + 8);
        int wa[8] = {a0.x, a0.y, a0.z, a0.w, a1.x, a1.y, a1.z, a1.w};
        int wb[8] = {b0.x, b0.y, b0.z, b0.w, b1.x, b1.y, b1.z, b1.w};
        #pragma unroll
        for (int i = 0; i < 8; ++i) {
            unsigned ua = (unsigned)wa[i], ub = (unsigned)wb[i];
            q[2*i+0] = bfu(ua & 0xFFFFu) + bfu(ub & 0xFFFFu) + sqb[qoff + 2*i+0];
            q[2*i+1] = bfu(ua >> 16)     + bfu(ub >> 16)     + sqb[qoff + 2*i+1];
        }
        #pragma unroll
        for (int d = 0; d < 16; ++d) ss += q[d] * q[d];
    }
    float rq = rsqrtf(ss * (1.f / 16.f) + 1e-6f);
    #pragma unroll
    for (int d = 0; d < 16; ++d) q[d] *= rq * snw[d];

    // k row, RMSNorm
    float k[16];
    float sk = 0.f;
    {
        const int koffb = NQ + hh * 16;
        int4 a0 = *(const int4*)(r0 + koffb);
        int4 a1 = *(const int4*)(r0 + koffb + 8);
        int4 b0 = *(const int4*)(r1 + koffb);
        int4 b1 = *(const int4*)(r1 + koffb + 8);
        int wa[8] = {a0.x, a0.y, a0.z, a0.w, a1.x, a1.y, a1.z, a1.w};
        int wb[8] = {b0.x, b0.y, b0.z, b0.w, b1.x, b1.y, b1.z, b1.w};
        #pragma unroll
        for (int i = 0; i < 8; ++i) {
            unsigned ua = (unsigned)wa[i], ub = (unsigned)wb[i];
            k[2*i+0] = bfu(ua & 0xFFFFu) + bfu(ub & 0xFFFFu);
            k[2*i+1] = bfu(ua >> 16)     + bfu(ub >> 16);
        }
        #pragma unroll
        for (int d = 0; d < 16; ++d) sk += k[d] * k[d];
    }
    float rk = rsqrtf(sk * (1.f / 16.f) + 1e-6f);

    // logit = k̂·q̂ / 4 + b
    float logit = 0.f;
    #pragma unroll
    for (int d = 0; d < 16; ++d) logit += (k[d] * rk * snw[16 + d]) * q[d];
    logit = logit * 0.25f + sb[hh * 4 + g];

    // sum over sink tokens
    float accum = 0.f;
    const float* kbh = skb + hh * 256;
    #pragma unroll
    for (int s = 0; s < 16; ++s) {
        float lb = 0.f;
        #pragma unroll
        for (int d = 0; d < 16; ++d) lb += kbh[s * 16 + d] * q[d];
        accum += __expf(lb * 0.25f - logit);
    }
    float r = 1.f / (1.f + accum);

    // mean over g (4 lanes), lane g==0 writes
    r += __shfl_xor(r, 1);
    r += __shfl_xor(r, 2);
    if (g == 0) out[(size_t)hh * NSEQ + tok] = r * 0.25f;
}

// ---- launch ---------------------------------------------------------------
extern "C" void kernel_launch(void* const* d_in, const int* in_sizes, int n_in,
                              void* d_out, int out_size, void* d_ws, size_t ws_size,
                              hipStream_t stream)
{
    const float* hid = (const float*)d_in[0];
    const float* qw  = (const float*)d_in[1];
    const float* qb  = (const float*)d_in[2];
    const float* kw  = (const float*)d_in[3];
    const float* qnw = (const float*)d_in[4];
    const float* knw = (const float*)d_in[5];
    const float* kb  = (const float*)d_in[6];
    const float* bb  = (const float*)d_in[7];
    float* out = (float*)d_out;

    u16* Wst = (u16*)d_ws;                                        // 5,242,880 B
    u16* P0  = (u16*)((char*)d_ws + (size_t)NCOL * KD * 2);       // 20,971,520 B
    u16* P1  = P0 + (size_t)NSEQ * NCOL;                          // 20,971,520 B

    wconv_kernel<<<WCONV_THREADS / 256, 256, 0, stream>>>(qw, kw, Wst);
    gemm_kernel<<<1024, 256, 0, stream>>>(hid, Wst, P0, P1);
    gate_kernel<<<NSEQ * 32 / 256, 256, 0, stream>>>(P0, P1, qb, qnw, knw, kb, bb, out);
}

// Round 16
// 156.714 us; speedup vs baseline: 2.4940x; 2.4940x over previous
//
#include <hip/hip_runtime.h>
#include <hip/hip_bf16.h>

typedef __attribute__((ext_vector_type(8))) short bf16x8;
typedef __attribute__((ext_vector_type(4))) float f32x4;
typedef unsigned short u16;

constexpr int NSEQ = 16384;
constexpr int KD   = 4096;
constexpr int NQ   = 512;     // q cols
constexpr int NCOL = 640;     // q (512) + k (128)
constexpr int BM   = 128;
constexpr int BN   = 320;
constexpr int BK   = 32;
constexpr int KHALF = 2048;
constexpr int NKS  = KHALF / BK;              // 64 K-steps per block
constexpr int TILE_CHUNKS = BN * BK * 2 / 16; // 1280 16B chunks per W tile
constexpr int TILE_U16    = TILE_CHUNKS * 8;  // 10240
constexpr int WCONV_THREADS = 2 * 2 * NKS * TILE_CHUNKS;   // 327,680

// ---- f32 -> bf16 (RTNE) pack helpers -------------------------------------
__device__ __forceinline__ unsigned bf_round(float x) {
    unsigned u = __builtin_bit_cast(unsigned, x);
    unsigned r = u + 0x7FFFu + ((u >> 16) & 1u);
    return r >> 16;
}
__device__ __forceinline__ unsigned pk2(float lo, float hi) {
    return bf_round(lo) | (bf_round(hi) << 16);
}
__device__ __forceinline__ float bfu(unsigned u) {
    return __builtin_bit_cast(float, u << 16);
}

// ---- Kernel 1: W -> bf16, pre-swizzled per-(kh,nb,tt) glds tiles ---------
// Tile = 320 rows x 32 k bf16 = 1280 chunks. Chunk c: n = c>>2, sp = c&3
// (physical slot). Content = logical slot sp ^ ((n>>1)&3) (R3 swizzle) =>
// after linear glds, LDS[n*64 + sp*16] holds logical slot sp^((n>>1)&3).
__global__ __launch_bounds__(256) void wconv_kernel(
    const float* __restrict__ qw, const float* __restrict__ kw,
    u16* __restrict__ Wst)
{
    int cg = blockIdx.x * 256 + threadIdx.x;
    int tile = cg / TILE_CHUNKS;         // 0..255 = kh*128 + nb*64 + tt
    int c    = cg - tile * TILE_CHUNKS;
    int n  = c >> 2;
    int sp = c & 3;
    int tt = tile & 63;
    int nb = (tile >> 6) & 1;
    int kh = tile >> 7;
    int ng = nb * BN + n;
    int k0 = kh * KHALF + tt * BK + ((sp ^ ((n >> 1) & 3)) << 3);
    const float* src = (ng < NQ) ? (qw + (size_t)ng * KD + k0)
                                 : (kw + (size_t)(ng - NQ) * KD + k0);
    float4 v0 = *(const float4*)(src);
    float4 v1 = *(const float4*)(src + 4);
    int4 o;
    o.x = (int)pk2(v0.x, v0.y);
    o.y = (int)pk2(v0.z, v0.w);
    o.z = (int)pk2(v1.x, v1.y);
    o.w = (int)pk2(v1.z, v1.w);
    *(int4*)(Wst + (size_t)cg * 8) = o;
}

// ---- Kernel 2: BM=128 x BN=320, K-split 2, dbuf glds + counted vmcnt -----
// grid 512 = 128 mblk x 2 nb x 2 kh; XCD b&7 owns (kh, nb). 512 thr = 8
// waves (2M x 4N), wave tile 64x80, acc[4][5]. LDS 57KB (A 8K + B 20K,
// each double-buffered) -> 2 blocks/CU. Per step: glds B(tt+1) 2-3 chunks
// + ds_write A(tt+1) + reg-prefetch A(tt+2), counted vmcnt(2) (exact:
// sched_barrier pins A-loads AFTER glds in the queue), 1 barrier.
__global__ __launch_bounds__(512, 4) void gemm_kernel(
    const float* __restrict__ hid, const u16* __restrict__ Wst,
    u16* __restrict__ P0, u16* __restrict__ P1)
{
    __shared__ __align__(16) char smem[2 * 8192 + 2 * 20480];   // 57,344 B
    char* sA = smem;
    char* sB = smem + 16384;

    const int t    = threadIdx.x;
    const int lane = t & 63;
    const int wid  = t >> 6;        // 0..7
    const int wm   = wid >> 2;      // 0..1 (64-row half)
    const int wn   = wid & 3;       // 0..3 (80-col slice)

    const int b    = blockIdx.x;
    const int xcd  = b & 7;
    const int kh   = xcd & 1;
    const int nb   = (xcd >> 1) & 1;
    const int mblk = (b >> 3) * 2 + (xcd >> 2);   // 0..127, bijective
    const int row0 = mblk * BM;
    const int col0 = nb * BN;

    const float* hk = hid + (size_t)row0 * KD + kh * KHALF;
    const u16* wt0  = Wst + (size_t)(kh * 128 + nb * 64) * TILE_U16;
    u16* P = kh ? P1 : P0;

    f32x4 acc[4][5] = {};

    // A staging (R3-proven): thread t -> row ar (0..127), slot ks8 (0..3)
    const int ar  = t >> 2;
    const int ks8 = t & 3;
    const float* gA = hk + (size_t)ar * KD + ks8 * 8;
    const int aWoff = ar * 64 + ((ks8 ^ ((ar >> 1) & 3)) << 4);

    // fragment read params (R3-proven, 0 conflicts)
    const int bn   = lane & 15;
    const int koff = (((lane >> 4) ^ ((bn >> 1) & 3)) << 4);

    float4 s0a, s0b, s1a, s1b;

#define GLDS(TT, BUF)                                                            \
    do {                                                                         \
        const u16* tp_ = wt0 + (size_t)(TT) * TILE_U16;                          \
        char* bb_ = sB + (BUF) * 20480;                                          \
        __builtin_amdgcn_global_load_lds(                                        \
            (const __attribute__((address_space(1))) void*)(tp_ + (size_t)t * 8), \
            (__attribute__((address_space(3))) void*)(bb_ + wid * 1024),         \
            16, 0, 0);                                                           \
        __builtin_amdgcn_global_load_lds(                                        \
            (const __attribute__((address_space(1))) void*)(tp_ + (size_t)(t + 512) * 8), \
            (__attribute__((address_space(3))) void*)(bb_ + 8192 + wid * 1024),  \
            16, 0, 0);                                                           \
        if (t < 256)                                                             \
            __builtin_amdgcn_global_load_lds(                                    \
                (const __attribute__((address_space(1))) void*)(tp_ + (size_t)(t + 1024) * 8), \
                (__attribute__((address_space(3))) void*)(bb_ + 16384 + wid * 1024), \
                16, 0, 0);                                                       \
    } while (0)

#define DSWA(BUF, Ra, Rb)                                                        \
    do {                                                                         \
        int4 ap_;                                                                \
        ap_.x = (int)pk2(Ra.x, Ra.y);  ap_.y = (int)pk2(Ra.z, Ra.w);             \
        ap_.z = (int)pk2(Rb.x, Rb.y);  ap_.w = (int)pk2(Rb.z, Rb.w);             \
        *(int4*)(sA + (BUF) * 8192 + aWoff) = ap_;                               \
    } while (0)

#define COMPUTE(CUR)                                                             \
    do {                                                                         \
        const char* sAc = sA + (CUR) * 8192;                                     \
        const char* sBc = sB + (CUR) * 20480;                                    \
        bf16x8 af[4];                                                            \
        _Pragma("unroll")                                                        \
        for (int m = 0; m < 4; ++m)                                              \
            af[m] = *(const bf16x8*)(sAc + (wm * 64 + m * 16 + bn) * 64 + koff); \
        _Pragma("unroll")                                                        \
        for (int f = 0; f < 5; ++f) {                                            \
            bf16x8 bfr = *(const bf16x8*)(sBc + (wn * 80 + f * 16 + bn) * 64 + koff); \
            acc[0][f] = __builtin_amdgcn_mfma_f32_16x16x32_bf16(af[0], bfr, acc[0][f], 0, 0, 0); \
            acc[1][f] = __builtin_amdgcn_mfma_f32_16x16x32_bf16(af[1], bfr, acc[1][f], 0, 0, 0); \
            acc[2][f] = __builtin_amdgcn_mfma_f32_16x16x32_bf16(af[2], bfr, acc[2][f], 0, 0, 0); \
            acc[3][f] = __builtin_amdgcn_mfma_f32_16x16x32_bf16(af[3], bfr, acc[3][f], 0, 0, 0); \
        }                                                                        \
    } while (0)

#define STEP(TT, CUR, SWa, SWb, SLa, SLb, HG, HA)                                \
    {                                                                            \
        if (HG) { GLDS((TT) + 1, (CUR) ^ 1); DSWA((CUR) ^ 1, SWa, SWb); }        \
        __builtin_amdgcn_sched_barrier(0);                                       \
        if (HA) { SLa = *(const float4*)(gA + ((TT) + 2) * BK);                  \
                  SLb = *(const float4*)(gA + ((TT) + 2) * BK + 4); }            \
        __builtin_amdgcn_sched_barrier(0);                                       \
        COMPUTE(CUR);                                                            \
        if ((HG) && (HA)) { asm volatile("s_waitcnt vmcnt(2) lgkmcnt(0)" ::: "memory"); } \
        else if (HG)      { asm volatile("s_waitcnt vmcnt(0) lgkmcnt(0)" ::: "memory"); } \
        else              { asm volatile("s_waitcnt lgkmcnt(0)" ::: "memory"); } \
        __builtin_amdgcn_s_barrier();                                            \
    }

    // ---- prologue: A(0) load+write -> buf0; glds tile0 -> buf0; A(1)->s0 ----
    {
        float4 a0 = *(const float4*)(gA);
        float4 a1 = *(const float4*)(gA + 4);
        DSWA(0, a0, a1);          // compiler waits a0/a1 (once)
    }
    GLDS(0, 0);
    __builtin_amdgcn_sched_barrier(0);
    s0a = *(const float4*)(gA + BK);
    s0b = *(const float4*)(gA + BK + 4);
    __builtin_amdgcn_sched_barrier(0);
    asm volatile("s_waitcnt vmcnt(2) lgkmcnt(0)" ::: "memory");
    __builtin_amdgcn_s_barrier();

    // ---- steady: tt = 0..61 ----
#pragma unroll 1
    for (int t2 = 0; t2 < 31; ++t2) {
        const int tt = t2 * 2;
        STEP(tt,     0, s0a, s0b, s1a, s1b, 1, 1)   // write A(tt+1)=s0, load A(tt+2)->s1
        STEP(tt + 1, 1, s1a, s1b, s0a, s0b, 1, 1)   // write A(tt+2)=s1, load A(tt+3)->s0
    }
    // ---- tail ----
    STEP(62, 0, s0a, s0b, s1a, s1b, 1, 0)   // stage tile 63 (A63=s0); full drain
    STEP(63, 1, s1a, s1b, s0a, s0b, 0, 0)   // pure compute
#undef GLDS
#undef DSWA
#undef COMPUTE
#undef STEP

    // epilogue: bf16 partial-P write. C/D: col=lane&15, row=(lane>>4)*4+j
    const int crow = (lane >> 4) << 2;
    const int ccol = lane & 15;
    #pragma unroll
    for (int m = 0; m < 4; ++m)
        #pragma unroll
        for (int f = 0; f < 5; ++f)
            #pragma unroll
            for (int j = 0; j < 4; ++j)
                P[(size_t)(row0 + wm * 64 + m * 16 + crow + j) * NCOL
                  + col0 + wn * 80 + f * 16 + ccol] = (u16)bf_round(acc[m][f][j]);
}

// ---- Kernel 3: gating epilogue (reads two bf16 partial-P halves) ----------
__global__ __launch_bounds__(256) void gate_kernel(
    const u16* __restrict__ P0, const u16* __restrict__ P1,
    const float* __restrict__ qb,
    const float* __restrict__ qnw, const float* __restrict__ knw,
    const float* __restrict__ kbase, const float* __restrict__ bb,
    float* __restrict__ out)
{
    __shared__ float skb[8 * 16 * 16];
    __shared__ float sqb[512];
    __shared__ float sb[32];
    __shared__ float snw[32];

    int tid = threadIdx.x;
    for (int i = tid; i < 2048; i += 256) skb[i] = kbase[i];
    for (int i = tid; i < 512;  i += 256) sqb[i] = qb[i];
    if (tid < 32) sb[tid] = bb[tid];
    if (tid < 16) snw[tid] = qnw[tid];
    else if (tid < 32) snw[tid] = knw[tid - 16];
    __syncthreads();

    int gid = blockIdx.x * 256 + tid;
    int tok = gid >> 5;
    int hh  = (gid >> 2) & 7;
    int g   = gid & 3;

    const u16* r0 = P0 + (size_t)tok * NCOL;
    const u16* r1 = P1 + (size_t)tok * NCOL;
    const int qoff = (hh * 4 + g) * 16;

    // q row = P0 + P1 + bias, then RMSNorm
    float q[16];
    float ss = 0.f;
    {
        int4 a0 = *(const int4*)(r0 + qoff);
        int4 a1 = *(const int4*)(r0 + qoff + 8);
        int4 b0 = *(const int4*)(r1 + qoff);
        int4 b1 = *(const int4*)(r1 + qoff + 8);
        int wa[8] = {a0.x, a0.y, a0.z, a0.w, a1.x, a1.y, a1.z, a1.w};
        int wb[8] = {b0.x, b0.y, b0.z, b0.w, b1.x, b1.y, b1.z, b1.w};
        #pragma unroll
        for (int i = 0; i < 8; ++i) {
            unsigned ua = (unsigned)wa[i], ub = (unsigned)wb[i];
            q[2*i+0] = bfu(ua & 0xFFFFu) + bfu(ub & 0xFFFFu) + sqb[qoff + 2*i+0];
            q[2*i+1] = bfu(ua >> 16)     + bfu(ub >> 16)     + sqb[qoff + 2*i+1];
        }
        #pragma unroll
        for (int d = 0; d < 16; ++d) ss += q[d] * q[d];
    }
    float rq = rsqrtf(ss * (1.f / 16.f) + 1e-6f);
    #pragma unroll
    for (int d = 0; d < 16; ++d) q[d] *= rq * snw[d];

    // k row, RMSNorm
    float k[16];
    float sk = 0.f;
    {
        const int koffb = NQ + hh * 16;
        int4 a0 = *(const int4*)(r0 + koffb);
        int4 a1 = *(const int4*)(r0 + koffb + 8);
        int4 b0 = *(const int4*)(r1 + koffb);
        int4 b1 = *(const int4*)(r1 + koffb + 8);
        int wa[8] = {a0.x, a0.y, a0.z, a0.w, a1.x, a1.y, a1.z, a1.w};
        int wb[8] = {b0.x, b0.y, b0.z, b0.w, b1.x, b1.y, b1.z, b1.w};
        #pragma unroll
        for (int i = 0; i < 8; ++i) {
            unsigned ua = (unsigned)wa[i], ub = (unsigned)wb[i];
            k[2*i+0] = bfu(ua & 0xFFFFu) + bfu(ub & 0xFFFFu);
            k[2*i+1] = bfu(ua >> 16)     + bfu(ub >> 16);
        }
        #pragma unroll
        for (int d = 0; d < 16; ++d) sk += k[d] * k[d];
    }
    float rk = rsqrtf(sk * (1.f / 16.f) + 1e-6f);

    // logit = k̂·q̂ / 4 + b
    float logit = 0.f;
    #pragma unroll
    for (int d = 0; d < 16; ++d) logit += (k[d] * rk * snw[16 + d]) * q[d];
    logit = logit * 0.25f + sb[hh * 4 + g];

    // sum over sink tokens
    float accum = 0.f;
    const float* kbh = skb + hh * 256;
    #pragma unroll
    for (int s = 0; s < 16; ++s) {
        float lb = 0.f;
        #pragma unroll
        for (int d = 0; d < 16; ++d) lb += kbh[s * 16 + d] * q[d];
        accum += __expf(lb * 0.25f - logit);
    }
    float r = 1.f / (1.f + accum);

    // mean over g (4 lanes), lane g==0 writes
    r += __shfl_xor(r, 1);
    r += __shfl_xor(r, 2);
    if (g == 0) out[(size_t)hh * NSEQ + tok] = r * 0.25f;
}

// ---- launch ---------------------------------------------------------------
extern "C" void kernel_launch(void* const* d_in, const int* in_sizes, int n_in,
                              void* d_out, int out_size, void* d_ws, size_t ws_size,
                              hipStream_t stream)
{
    const float* hid = (const float*)d_in[0];
    const float* qw  = (const float*)d_in[1];
    const float* qb  = (const float*)d_in[2];
    const float* kw  = (const float*)d_in[3];
    const float* qnw = (const float*)d_in[4];
    const float* knw = (const float*)d_in[5];
    const float* kb  = (const float*)d_in[6];
    const float* bb  = (const float*)d_in[7];
    float* out = (float*)d_out;

    u16* Wst = (u16*)d_ws;                                        // 5,242,880 B
    u16* P0  = (u16*)((char*)d_ws + (size_t)NCOL * KD * 2);       // 20,971,520 B
    u16* P1  = P0 + (size_t)NSEQ * NCOL;                          // 20,971,520 B

    wconv_kernel<<<WCONV_THREADS / 256, 256, 0, stream>>>(qw, kw, Wst);
    gemm_kernel<<<512, 512, 0, stream>>>(hid, Wst, P0, P1);
    gate_kernel<<<NSEQ * 32 / 256, 256, 0, stream>>>(P0, P1, qb, qnw, knw, kb, bb, out);
}